// Round 5
// baseline (5019.843 us; speedup 1.0000x reference)
//
#include <hip/hip_runtime.h>
#include <math.h>

#define SEQ 96
#define EMB 768
#define G4  3072   // 4*H
#define NLAYER 95  // conv layers
#define CKP 264    // xs col pitch (bf16 elems): 256 k-chunk + 8 pad
#define CONV_WG 48
#define LSTM_WG 192
#define XPITCH 1536  // ushorts per col in x buffers: 48 blocks x (hi16|lo16)

typedef float  f32x4  __attribute__((ext_vector_type(4)));
typedef short  bf16x8 __attribute__((ext_vector_type(8)));

union BF8 { unsigned short u[8]; bf16x8 v; };

__device__ __forceinline__ unsigned short f2bf(float f) {   // RNE fp32->bf16
    unsigned u = __float_as_uint(f);
    u += 0x7FFFu + ((u >> 16) & 1u);
    return (unsigned short)(u >> 16);
}
__device__ __forceinline__ float bf2f(unsigned short u) {
    return __uint_as_float(((unsigned)u) << 16);
}

// ---------------- centralized 2-phase grid barrier (LSTM) -----------------
__device__ __forceinline__ void cbar(unsigned* flags, unsigned* epoch,
                                     int nwg, int wg, unsigned target) {
    __threadfence();              // release prior global writes
    __syncthreads();
    if (threadIdx.x == 0)
        __hip_atomic_store(&flags[wg], target,
                           __ATOMIC_RELAXED, __HIP_MEMORY_SCOPE_AGENT);
    if (wg == 0) {
        for (int i = threadIdx.x; i < nwg; i += blockDim.x)
            while (__hip_atomic_load(&flags[i], __ATOMIC_RELAXED,
                                     __HIP_MEMORY_SCOPE_AGENT) < target)
                __builtin_amdgcn_s_sleep(2);
        __syncthreads();
        if (threadIdx.x == 0)
            __hip_atomic_store(epoch, target,
                               __ATOMIC_RELAXED, __HIP_MEMORY_SCOPE_AGENT);
    }
    if (threadIdx.x == 0)
        while (__hip_atomic_load(epoch, __ATOMIC_RELAXED,
                                 __HIP_MEMORY_SCOPE_AGENT) < target)
            __builtin_amdgcn_s_sleep(2);
    __threadfence();              // acquire
    __syncthreads();
}

__device__ __forceinline__ float red16(float a) {
    a += __shfl_xor(a, 8, 16);
    a += __shfl_xor(a, 4, 16);
    a += __shfl_xor(a, 2, 16);
    a += __shfl_xor(a, 1, 16);
    return a;
}

__device__ __forceinline__ float sigmoidf_(float x) {
    return 1.0f / (1.0f + __expf(-x));
}

// ---------------- emb2 gather -> hi/lo bf16 x0 ----------------------------
__global__ void k_embed(const int* __restrict__ xids,
                        const float* __restrict__ emb2,
                        unsigned short* __restrict__ x0) {
    const int col = blockIdx.x;                 // 96 blocks
    const int tok = xids[col];
    const int tid = threadIdx.x;
    if (tid < 192) {
        float4 v = *(const float4*)(emb2 + (size_t)tok * EMB + tid * 4);
        ushort4 hv, lv;
        hv.x = f2bf(v.x); lv.x = f2bf(v.x - bf2f(hv.x));
        hv.y = f2bf(v.y); lv.y = f2bf(v.y - bf2f(hv.y));
        hv.z = f2bf(v.z); lv.z = f2bf(v.z - bf2f(hv.z));
        hv.w = f2bf(v.w); lv.w = f2bf(v.w - bf2f(hv.w));
        unsigned short* base = x0 + col * XPITCH + (tid >> 2) * 32 + (tid & 3) * 4;
        *(ushort4*)base        = hv;
        *(ushort4*)(base + 16) = lv;
    }
}

// ---------------- A1[t][row] = Wih1@emb1[x_t] + bih1 + bhh1 ---------------
__global__ __launch_bounds__(256) void k_a1(const int* __restrict__ xids,
                                            const float* __restrict__ emb1,
                                            const float* __restrict__ wih,
                                            const float* __restrict__ bih,
                                            const float* __restrict__ bhh,
                                            float* __restrict__ A1) {
    __shared__ float sx[EMB];
    const int tid = threadIdx.x;
    const int l16 = tid & 15;
    const int r16 = tid >> 4;
    const int row = blockIdx.x * 16 + r16;      // 192 blocks x 16 rows
    float w[48];
#pragma unroll
    for (int i = 0; i < 48; ++i)
        w[i] = wih[(size_t)row * EMB + l16 + (i << 4)];
    const float bsum = bih[row] + bhh[row];
    for (int t = 0; t < SEQ; ++t) {
        const int tok = xids[t];
        __syncthreads();
        if (tid < 192) {
            float4 v = *(const float4*)(emb1 + (size_t)tok * EMB + tid * 4);
            *(float4*)(sx + tid * 4) = v;
        }
        __syncthreads();
        float a = 0.f;
#pragma unroll
        for (int i = 0; i < 48; ++i)
            a = fmaf(w[i], sx[l16 + (i << 4)], a);
        a = red16(a);
        if (l16 == 0) A1[t * G4 + row] = a + bsum;
    }
}

// ---- issue one layer's 16-row weight slab into registers (24 float4) -----
#define ISSUE_W(LAY, WREG) do {                                              \
    const float* wsl_ = conv_w + (size_t)(LAY) * (EMB * EMB * 2)             \
                               + (size_t)(r0 + lj) * (EMB * 2);              \
    _Pragma("unroll")                                                        \
    for (int ch_ = 0; ch_ < 3; ++ch_) {                                      \
        _Pragma("unroll")                                                    \
        for (int s_ = 0; s_ < 2; ++s_) {                                     \
            const int K0_ = (ch_ * 8 + wv * 2 + s_) * 32;                    \
            const float4* ap_ =                                              \
                (const float4*)(wsl_ + (size_t)(K0_ + lg * 8) * 2);          \
            _Pragma("unroll")                                                \
            for (int j_ = 0; j_ < 4; ++j_) WREG[ch_][s_][j_] = ap_[j_];      \
        }                                                                    \
    }                                                                        \
} while (0)

// ---- full conv layer using Wc; prefetch LAY+1 into Wn inside barrier -----
#define CONV_LAYER(LAY, Wc, Wn) do {                                         \
    const int ncols = NLAYER - (LAY);                                        \
    const int scols = (ncols + 1 < 96) ? ncols + 1 : 96;                     \
    const int nts   = (ncols + 15) >> 4;                                     \
    const unsigned short* src = ((LAY) & 1) ? x1buf : x0buf;                 \
    unsigned short*       dst = ((LAY) & 1) ? x0buf : x1buf;                 \
    f32x4 acc[6];                                                            \
    _Pragma("unroll")                                                        \
    for (int n = 0; n < 6; ++n) acc[n] = (f32x4)0.f;                         \
    _Pragma("unroll")                                                        \
    for (int ch = 0; ch < 3; ++ch) {                                         \
        _Pragma("unroll")                                                    \
        for (int j = 0; j < 12; ++j) {                                       \
            const int u = tid + j * 256;                                     \
            const int c = u >> 5, q = u & 31;                                \
            if (c < scols) {                                                 \
                const int k = ch * 256 + q * 8;                              \
                const unsigned short* sp =                                   \
                    src + c * XPITCH + ((k >> 4) << 5) + (k & 15);           \
                bf16x8 vh = *(const bf16x8*)sp;                              \
                bf16x8 vl = *(const bf16x8*)(sp + 16);                       \
                *(bf16x8*)(xs_hi + c * CKP + q * 8) = vh;                    \
                *(bf16x8*)(xs_lo + c * CKP + q * 8) = vl;                    \
            }                                                                \
        }                                                                    \
        __syncthreads();                                                     \
        _Pragma("unroll")                                                    \
        for (int s = 0; s < 2; ++s) {                                        \
            const int klocal = (wv * 2 + s) * 32;                            \
            BF8 a0h, a0l, a1h, a1l;                                          \
            _Pragma("unroll")                                                \
            for (int d = 0; d < 8; ++d) {                                    \
                const float4 f = Wc[ch][s][d >> 1];                          \
                const float w0 = (d & 1) ? f.z : f.x;                        \
                const float w1 = (d & 1) ? f.w : f.y;                        \
                const unsigned short h0 = f2bf(w0);                          \
                const unsigned short h1 = f2bf(w1);                          \
                a0h.u[d] = h0; a0l.u[d] = f2bf(w0 - bf2f(h0));               \
                a1h.u[d] = h1; a1l.u[d] = f2bf(w1 - bf2f(h1));               \
            }                                                                \
            _Pragma("unroll")                                                \
            for (int nt = 0; nt < 6; ++nt) if (nt < nts) {                   \
                const int co = (nt * 16 + lj) * CKP + klocal + lg * 8;       \
                bf16x8 bh0 = *(const bf16x8*)(xs_hi + co);                   \
                bf16x8 bl0 = *(const bf16x8*)(xs_lo + co);                   \
                bf16x8 bh1 = *(const bf16x8*)(xs_hi + co + CKP);             \
                bf16x8 bl1 = *(const bf16x8*)(xs_lo + co + CKP);             \
                acc[nt] = __builtin_amdgcn_mfma_f32_16x16x32_bf16(           \
                              a0h.v, bh0, acc[nt], 0, 0, 0);                 \
                acc[nt] = __builtin_amdgcn_mfma_f32_16x16x32_bf16(           \
                              a0h.v, bl0, acc[nt], 0, 0, 0);                 \
                acc[nt] = __builtin_amdgcn_mfma_f32_16x16x32_bf16(           \
                              a0l.v, bh0, acc[nt], 0, 0, 0);                 \
                acc[nt] = __builtin_amdgcn_mfma_f32_16x16x32_bf16(           \
                              a1h.v, bh1, acc[nt], 0, 0, 0);                 \
                acc[nt] = __builtin_amdgcn_mfma_f32_16x16x32_bf16(           \
                              a1h.v, bl1, acc[nt], 0, 0, 0);                 \
                acc[nt] = __builtin_amdgcn_mfma_f32_16x16x32_bf16(           \
                              a1l.v, bh1, acc[nt], 0, 0, 0);                 \
            }                                                                \
        }                                                                    \
        __syncthreads();                                                     \
    }                                                                        \
    _Pragma("unroll")                                                        \
    for (int nt = 0; nt < 6; ++nt) if (nt < nts)                             \
        *(f32x4*)&part[wv * 1536 + (nt * 16 + lj) * 16 + lg * 4] = acc[nt];  \
    __syncthreads();                                                         \
    _Pragma("unroll")                                                        \
    for (int j = 0; j < 6; ++j) {                                            \
        const int o = tid + j * 256;                                         \
        const int c = o >> 4, i = o & 15;                                    \
        if (c < ncols) {                                                     \
            float sv = part[o] + part[1536 + o] + part[3072 + o]             \
                     + part[4608 + o] + conv_b[(LAY) * EMB + r0 + i];        \
            sv = fmaxf(sv, 0.f);                                             \
            const unsigned short sh = f2bf(sv);                              \
            const unsigned short sl = f2bf(sv - bf2f(sh));                   \
            dst[c * XPITCH + bI * 32 + i]      = sh;                         \
            dst[c * XPITCH + bI * 32 + 16 + i] = sl;                         \
            if ((LAY) == NLAYER - 1 && c == 0)                               \
                dout[3074 + r0 + i] = sv;                                    \
        }                                                                    \
    }                                                                        \
    if ((LAY) + 1 < NLAYER) {                                                \
        const unsigned tgt = (unsigned)((LAY) + 1);                          \
        __threadfence();           /* release (drains vmcnt) */              \
        __syncthreads();                                                     \
        if (tid == 0)                                                        \
            __hip_atomic_store(&cflags[bI], tgt,                             \
                               __ATOMIC_RELAXED, __HIP_MEMORY_SCOPE_AGENT);  \
        ISSUE_W((LAY) + 1, Wn);    /* stream next layer during barrier */    \
        asm volatile("" ::: "memory");  /* pin issue point */                \
        if (bI == 0) {                                                       \
            for (int i = tid; i < CONV_WG; i += 256)                         \
                while (__hip_atomic_load(&cflags[i], __ATOMIC_RELAXED,       \
                                         __HIP_MEMORY_SCOPE_AGENT) < tgt)    \
                    __builtin_amdgcn_s_sleep(2);                             \
            __syncthreads();                                                 \
            if (tid == 0)                                                    \
                __hip_atomic_store(cepoch, tgt,                              \
                                   __ATOMIC_RELAXED,                         \
                                   __HIP_MEMORY_SCOPE_AGENT);                \
        }                                                                    \
        if (tid == 0)                                                        \
            while (__hip_atomic_load(cepoch, __ATOMIC_RELAXED,               \
                                     __HIP_MEMORY_SCOPE_AGENT) < tgt)        \
                __builtin_amdgcn_s_sleep(2);                                 \
        __threadfence();           /* acquire */                             \
        __syncthreads();                                                     \
    }                                                                        \
} while (0)

// ---------------- fused persistent kernel: 48 conv WGs + 192 LSTM WGs -----
__global__ __launch_bounds__(256, 1) void k_net(
    const float* __restrict__ conv_w, const float* __restrict__ conv_b,
    unsigned short* __restrict__ x0buf, unsigned short* __restrict__ x1buf,
    const float* __restrict__ hstate, const float* __restrict__ cstate,
    const float* __restrict__ wih, const float* __restrict__ whh,
    const float* __restrict__ bih, const float* __restrict__ bhh,
    const float* __restrict__ A1,
    float* __restrict__ h1buf, float* __restrict__ h2buf,
    unsigned* __restrict__ cflags, unsigned* __restrict__ cepoch,
    unsigned* __restrict__ lflags, unsigned* __restrict__ lepoch,
    float* __restrict__ dout) {

    __shared__ __align__(16) unsigned short xs_hi[97 * CKP];   // 51216 B
    __shared__ __align__(16) unsigned short xs_lo[97 * CKP];   // 51216 B
    __shared__ float part[4 * 16 * 96];                        // 24576 B
    __shared__ float hx[EMB], hb2[EMB];
    __shared__ float g1s[16], g2s[16], c1s[4], c2s[4];

    const int tid = threadIdx.x;

    if (blockIdx.x < CONV_WG) {
        // ================= conv path: 16-row slab, split-bf16 MFMA ========
        const int wv = tid >> 6;           // wave 0..3 (K-split)
        const int ln = tid & 63;
        const int lj = ln & 15;            // A-row / B-col lane index
        const int lg = ln >> 4;            // k-group 0..3
        const int bI = blockIdx.x;
        const int r0 = bI * 16;

        float4 Wa[3][2][4], Wb[3][2][4];   // double-buffered weight slab
        ISSUE_W(0, Wa);

#pragma unroll 1
        for (int lay = 0; lay + 1 < NLAYER; lay += 2) {
            CONV_LAYER(lay, Wa, Wb);
            CONV_LAYER(lay + 1, Wb, Wa);
        }
        CONV_LAYER(NLAYER - 1, Wa, Wb);    // lay=94 (even), no prefetch
    } else {
        // ================= LSTM path: 97 ticks, skewed layers =============
        const int wg   = blockIdx.x - CONV_WG;    // 0..191
        const int l16  = tid & 15;
        const int r16  = tid >> 4;
        const int gate = r16 >> 2;
        const int jl   = r16 & 3;
        const int j0   = wg * 4;
        const int grow = gate * EMB + j0 + jl;

        float wh1r[48], wi2r[48], wh2r[48];
        const float* whh1 = whh;
        const float* wih2 = wih + (size_t)G4 * EMB;
        const float* whh2 = whh + (size_t)G4 * EMB;
#pragma unroll
        for (int i = 0; i < 48; ++i) {
            const int k = l16 + (i << 4);
            wh1r[i] = whh1[(size_t)grow * EMB + k];
            wi2r[i] = wih2[(size_t)grow * EMB + k];
            wh2r[i] = whh2[(size_t)grow * EMB + k];
        }
        const float b2 = bih[G4 + grow] + bhh[G4 + grow];

        if (tid < 4)      c1s[tid]     = cstate[j0 + tid];
        else if (tid < 8) c2s[tid - 4] = cstate[EMB + j0 + (tid - 4)];
        __syncthreads();

        for (int T = 0; T <= SEQ; ++T) {
            if (tid < 192) {
                float4 hv = (T == 0)
                    ? *(const float4*)(hstate + tid * 4)
                    : *(const float4*)(h1buf + (T - 1) * EMB + tid * 4);
                float4 h2v = make_float4(0.f, 0.f, 0.f, 0.f);
                if (T >= 1)
                    h2v = (T == 1)
                        ? *(const float4*)(hstate + EMB + tid * 4)
                        : *(const float4*)(h2buf + (T - 2) * EMB + tid * 4);
                *(float4*)(hx + tid * 4)  = hv;
                *(float4*)(hb2 + tid * 4) = h2v;
            }
            __syncthreads();

            if (T < SEQ) {           // layer 1, step T
                float a = 0.f;
#pragma unroll
                for (int i = 0; i < 48; ++i)
                    a = fmaf(wh1r[i], hx[l16 + (i << 4)], a);
                a = red16(a);
                if (l16 == 0) g1s[r16] = a + A1[T * G4 + grow];
            }
            if (T >= 1) {            // layer 2, step T-1
                float b = 0.f;
#pragma unroll
                for (int i = 0; i < 48; ++i)
                    b = fmaf(wi2r[i], hx[l16 + (i << 4)], b);
#pragma unroll
                for (int i = 0; i < 48; ++i)
                    b = fmaf(wh2r[i], hb2[l16 + (i << 4)], b);
                b = red16(b);
                if (l16 == 0) g2s[r16] = b + b2;
            }
            __syncthreads();

            if (tid < 4 && T < SEQ) {
                const int j = tid;
                const float i_ = sigmoidf_(g1s[j]);
                const float f_ = sigmoidf_(g1s[4 + j]);
                const float g_ = tanhf(g1s[8 + j]);
                const float o_ = sigmoidf_(g1s[12 + j]);
                const float c  = f_ * c1s[j] + i_ * g_;
                c1s[j] = c;
                const float h = o_ * tanhf(c);
                __hip_atomic_store(&h1buf[T * EMB + j0 + j], h,
                                   __ATOMIC_RELAXED, __HIP_MEMORY_SCOPE_AGENT);
                if (T == SEQ - 1) {
                    dout[1 + j0 + j]    = h;   // h[0]
                    dout[1537 + j0 + j] = c;   // c[0]
                }
            } else if (tid >= 4 && tid < 8 && T >= 1) {
                const int j = tid - 4;
                const int s = T - 1;
                const float i_ = sigmoidf_(g2s[j]);
                const float f_ = sigmoidf_(g2s[4 + j]);
                const float g_ = tanhf(g2s[8 + j]);
                const float o_ = sigmoidf_(g2s[12 + j]);
                const float c  = f_ * c2s[j] + i_ * g_;
                c2s[j] = c;
                const float h = o_ * tanhf(c);
                __hip_atomic_store(&h2buf[s * EMB + j0 + j], h,
                                   __ATOMIC_RELAXED, __HIP_MEMORY_SCOPE_AGENT);
                if (s == SEQ - 1) {
                    dout[1 + EMB + j0 + j]    = h;   // h[1]
                    dout[1537 + EMB + j0 + j] = c;   // c[1]
                }
            }
            if (T < SEQ)
                cbar(lflags, lepoch, LSTM_WG, wg, (unsigned)(T + 1));
        }
    }
}

// ---------------- deterministic scalar epilogue ---------------------------
__global__ void k_final(const float* __restrict__ pred_w,
                        const float* __restrict__ pred_b,
                        const float* __restrict__ m2w,
                        const float* __restrict__ m2b,
                        const float* __restrict__ prev,
                        float* __restrict__ dout) {
    __shared__ float red[256];
    const int tid = threadIdx.x;
    float p1 = 0.f;
    for (int idx = tid; idx < 2 * EMB; idx += 256) {
        const int l = idx / EMB;
        const int j = idx - l * EMB;
        p1 += dout[1537 + idx] * pred_w[j * 2 + l];   // feat = c.T interleave
    }
    float p2 = 0.f;
    for (int e = tid; e < EMB; e += 256)
        p2 += dout[3074 + e] * m2w[2 * e] + prev[e] * m2w[2 * e + 1];

    red[tid] = p1;
    __syncthreads();
    for (int s = 128; s > 0; s >>= 1) {
        if (tid < s) red[tid] += red[tid + s];
        __syncthreads();
    }
    if (tid == 0) dout[0] = red[0] + pred_b[0];
    __syncthreads();
    red[tid] = p2;
    __syncthreads();
    for (int s = 128; s > 0; s >>= 1) {
        if (tid < s) red[tid] += red[tid + s];
        __syncthreads();
    }
    if (tid == 0) dout[3073] = red[0] + m2b[0];
}

extern "C" void kernel_launch(void* const* d_in, const int* in_sizes, int n_in,
                              void* d_out, int out_size, void* d_ws, size_t ws_size,
                              hipStream_t stream) {
    const int*   x      = (const int*)d_in[0];
    const float* hstate = (const float*)d_in[1];
    const float* cstate = (const float*)d_in[2];
    const float* prev   = (const float*)d_in[3];
    const float* emb1   = (const float*)d_in[4];
    const float* emb2   = (const float*)d_in[5];
    const float* wih    = (const float*)d_in[6];
    const float* whh    = (const float*)d_in[7];
    const float* bih    = (const float*)d_in[8];
    const float* bhh    = (const float*)d_in[9];
    const float* predw  = (const float*)d_in[10];
    const float* predb  = (const float*)d_in[11];
    const float* convw  = (const float*)d_in[12];
    const float* convb  = (const float*)d_in[13];
    const float* m2w    = (const float*)d_in[14];
    const float* m2b    = (const float*)d_in[15];
    float* out = (float*)d_out;

    unsigned* wsw = (unsigned*)d_ws;
    unsigned* cflags = wsw;            // [0..48)
    unsigned* cepoch = wsw + 64;
    unsigned* lflags = wsw + 128;      // [128..320)
    unsigned* lepoch = wsw + 384;
    float* base  = (float*)d_ws + 1024;
    float* A1    = base;                               // 96*3072 f32
    float* h1buf = A1 + SEQ * G4;                      // 96*768 f32
    float* h2buf = h1buf + SEQ * EMB;                  // 96*768 f32
    unsigned short* x0buf = (unsigned short*)(h2buf + SEQ * EMB); // 96*1536 u16
    unsigned short* x1buf = x0buf + SEQ * XPITCH;                 // 96*1536 u16

    hipMemsetAsync(d_ws, 0, 4096, stream);                   // flags + epochs
    hipMemsetAsync(d_out, 0, out_size * sizeof(float), stream);

    k_embed<<<96, 256, 0, stream>>>(x, emb2, x0buf);
    k_a1<<<192, 256, 0, stream>>>(x, emb1, wih, bih, bhh, A1);
    k_net<<<CONV_WG + LSTM_WG, 256, 0, stream>>>(
        convw, convb, x0buf, x1buf,
        hstate, cstate, wih, whh, bih, bhh, A1, h1buf, h2buf,
        cflags, cepoch, lflags, lepoch, out);
    k_final<<<1, 256, 0, stream>>>(predw, predb, m2w, m2b, prev, out);
}

// Round 7
// 2383.912 us; speedup vs baseline: 2.1057x; 2.1057x over previous
//
#include <hip/hip_runtime.h>
#include <math.h>

#define SEQ 96
#define EMB 768
#define G4  3072   // 4*H
#define NLAYER 95  // conv layers
#define CKP 264    // xs col pitch (bf16 elems): 256 k-chunk + 8 pad
#define CONV_WG 48
#define LSTM_WG 192
#define XPITCH 1536  // ushorts per col in x buffers: 48 blocks x (hi16|lo16)

typedef float  f32x4  __attribute__((ext_vector_type(4)));
typedef short  bf16x8 __attribute__((ext_vector_type(8)));
typedef unsigned long long ull;

union BF8 { unsigned short u[8]; bf16x8 v; };

__device__ __forceinline__ unsigned short f2bf(float f) {   // RNE fp32->bf16
    unsigned u = __float_as_uint(f);
    u += 0x7FFFu + ((u >> 16) & 1u);
    return (unsigned short)(u >> 16);
}
__device__ __forceinline__ float bf2f(unsigned short u) {
    return __uint_as_float(((unsigned)u) << 16);
}

// ---- coherent (LLC-level, sc1) per-access data movement: no fences -------
__device__ __forceinline__ ull ld64g(const void* p) {
    return __hip_atomic_load((const ull*)p, __ATOMIC_RELAXED,
                             __HIP_MEMORY_SCOPE_AGENT);
}
__device__ __forceinline__ void st32g(void* p, unsigned v) {
    __hip_atomic_store((unsigned*)p, v, __ATOMIC_RELAXED,
                       __HIP_MEMORY_SCOPE_AGENT);
}
__device__ __forceinline__ void stf32g(float* p, float v) {
    __hip_atomic_store((unsigned*)p, __float_as_uint(v), __ATOMIC_RELAXED,
                       __HIP_MEMORY_SCOPE_AGENT);
}
__device__ __forceinline__ unsigned ldflag(const unsigned* p) {
    return __hip_atomic_load(p, __ATOMIC_RELAXED, __HIP_MEMORY_SCOPE_AGENT);
}
__device__ __forceinline__ void stflag(unsigned* p, unsigned v) {
    __hip_atomic_store(p, v, __ATOMIC_RELAXED, __HIP_MEMORY_SCOPE_AGENT);
}

// ---------------- fence-free grid barrier (data moves via sc1 atomics) ----
__device__ __forceinline__ void relbar(unsigned* flags, unsigned* epoch,
                                       int nwg, int wg, unsigned target) {
    asm volatile("s_waitcnt vmcnt(0)" ::: "memory");  // own sc1 stores done
    __syncthreads();
    if (threadIdx.x == 0) stflag(&flags[wg], target);
    if (wg == 0) {
        for (int i = threadIdx.x; i < nwg; i += blockDim.x)
            while (ldflag(&flags[i]) < target) __builtin_amdgcn_s_sleep(1);
        __syncthreads();
        if (threadIdx.x == 0) stflag(epoch, target);
    }
    if (threadIdx.x == 0)
        while (ldflag(epoch) < target) __builtin_amdgcn_s_sleep(1);
    asm volatile("" ::: "memory");
    __syncthreads();
}

__device__ __forceinline__ float red16(float a) {
    a += __shfl_xor(a, 8, 16);
    a += __shfl_xor(a, 4, 16);
    a += __shfl_xor(a, 2, 16);
    a += __shfl_xor(a, 1, 16);
    return a;
}

__device__ __forceinline__ float sigmoidf_(float x) {
    return 1.0f / (1.0f + __expf(-x));
}

// ---------------- emb2 gather -> hi/lo bf16 x0 ----------------------------
__global__ void k_embed(const int* __restrict__ xids,
                        const float* __restrict__ emb2,
                        unsigned short* __restrict__ x0) {
    const int col = blockIdx.x;                 // 96 blocks
    const int tok = xids[col];
    const int tid = threadIdx.x;
    if (tid < 192) {
        float4 v = *(const float4*)(emb2 + (size_t)tok * EMB + tid * 4);
        ushort4 hv, lv;
        hv.x = f2bf(v.x); lv.x = f2bf(v.x - bf2f(hv.x));
        hv.y = f2bf(v.y); lv.y = f2bf(v.y - bf2f(hv.y));
        hv.z = f2bf(v.z); lv.z = f2bf(v.z - bf2f(hv.z));
        hv.w = f2bf(v.w); lv.w = f2bf(v.w - bf2f(hv.w));
        unsigned short* base = x0 + col * XPITCH + (tid >> 2) * 32 + (tid & 3) * 4;
        *(ushort4*)base        = hv;
        *(ushort4*)(base + 16) = lv;
    }
}

// ---- issue one layer's 16-row weight slab into registers (24 float4) -----
#define ISSUE_W(LAY, WREG) do {                                              \
    const float* wsl_ = conv_w + (size_t)(LAY) * (EMB * EMB * 2)             \
                               + (size_t)(r0 + lj) * (EMB * 2);              \
    _Pragma("unroll")                                                        \
    for (int ch_ = 0; ch_ < 3; ++ch_) {                                      \
        _Pragma("unroll")                                                    \
        for (int s_ = 0; s_ < 2; ++s_) {                                     \
            const int K0_ = (ch_ * 8 + wv * 2 + s_) * 32;                    \
            const float4* ap_ =                                              \
                (const float4*)(wsl_ + (size_t)(K0_ + lg * 8) * 2);          \
            _Pragma("unroll")                                                \
            for (int j_ = 0; j_ < 4; ++j_) WREG[ch_][s_][j_] = ap_[j_];      \
        }                                                                    \
    }                                                                        \
} while (0)

// ---- full conv layer using Wc; prefetch LAY+1 into Wn inside barrier -----
#define CONV_LAYER(LAY, Wc, Wn) do {                                         \
    const int ncols = NLAYER - (LAY);                                        \
    const int scols = (ncols + 1 < 96) ? ncols + 1 : 96;                     \
    const int nts   = (ncols + 15) >> 4;                                     \
    const unsigned short* src = ((LAY) & 1) ? x1buf : x0buf;                 \
    unsigned short*       dst = ((LAY) & 1) ? x0buf : x1buf;                 \
    f32x4 acc[6];                                                            \
    _Pragma("unroll")                                                        \
    for (int n = 0; n < 6; ++n) acc[n] = (f32x4)0.f;                         \
    _Pragma("unroll")                                                        \
    for (int ch = 0; ch < 3; ++ch) {                                         \
        _Pragma("unroll")                                                    \
        for (int j = 0; j < 12; ++j) {                                       \
            const int u = tid + j * 256;                                     \
            const int c = u >> 5, q = u & 31;                                \
            if (c < scols) {                                                 \
                const int k = ch * 256 + q * 8;                              \
                const unsigned short* sp =                                   \
                    src + c * XPITCH + ((k >> 4) << 5) + (k & 15);           \
                ull h0 = ld64g(sp);                                          \
                ull h1 = ld64g(sp + 4);                                      \
                ull l0 = ld64g(sp + 16);                                     \
                ull l1 = ld64g(sp + 20);                                     \
                *(ull*)(xs_hi + c * CKP + q * 8)     = h0;                   \
                *(ull*)(xs_hi + c * CKP + q * 8 + 4) = h1;                   \
                *(ull*)(xs_lo + c * CKP + q * 8)     = l0;                   \
                *(ull*)(xs_lo + c * CKP + q * 8 + 4) = l1;                   \
            }                                                                \
        }                                                                    \
        __syncthreads();                                                     \
        _Pragma("unroll")                                                    \
        for (int s = 0; s < 2; ++s) {                                        \
            const int klocal = (wv * 2 + s) * 32;                            \
            BF8 a0h, a0l, a1h, a1l;                                          \
            _Pragma("unroll")                                                \
            for (int d = 0; d < 8; ++d) {                                    \
                const float4 f = Wc[ch][s][d >> 1];                          \
                const float w0 = (d & 1) ? f.z : f.x;                        \
                const float w1 = (d & 1) ? f.w : f.y;                        \
                const unsigned short h0 = f2bf(w0);                          \
                const unsigned short h1 = f2bf(w1);                          \
                a0h.u[d] = h0; a0l.u[d] = f2bf(w0 - bf2f(h0));               \
                a1h.u[d] = h1; a1l.u[d] = f2bf(w1 - bf2f(h1));               \
            }                                                                \
            _Pragma("unroll")                                                \
            for (int nt = 0; nt < 6; ++nt) if (nt < nts) {                   \
                const int co = (nt * 16 + lj) * CKP + klocal + lg * 8;       \
                bf16x8 bh0 = *(const bf16x8*)(xs_hi + co);                   \
                bf16x8 bl0 = *(const bf16x8*)(xs_lo + co);                   \
                bf16x8 bh1 = *(const bf16x8*)(xs_hi + co + CKP);             \
                bf16x8 bl1 = *(const bf16x8*)(xs_lo + co + CKP);             \
                acc[nt] = __builtin_amdgcn_mfma_f32_16x16x32_bf16(           \
                              a0h.v, bh0, acc[nt], 0, 0, 0);                 \
                acc[nt] = __builtin_amdgcn_mfma_f32_16x16x32_bf16(           \
                              a0h.v, bl0, acc[nt], 0, 0, 0);                 \
                acc[nt] = __builtin_amdgcn_mfma_f32_16x16x32_bf16(           \
                              a0l.v, bh0, acc[nt], 0, 0, 0);                 \
                acc[nt] = __builtin_amdgcn_mfma_f32_16x16x32_bf16(           \
                              a1h.v, bh1, acc[nt], 0, 0, 0);                 \
                acc[nt] = __builtin_amdgcn_mfma_f32_16x16x32_bf16(           \
                              a1h.v, bl1, acc[nt], 0, 0, 0);                 \
                acc[nt] = __builtin_amdgcn_mfma_f32_16x16x32_bf16(           \
                              a1l.v, bh1, acc[nt], 0, 0, 0);                 \
            }                                                                \
        }                                                                    \
        __syncthreads();                                                     \
    }                                                                        \
    _Pragma("unroll")                                                        \
    for (int nt = 0; nt < 6; ++nt) if (nt < nts)                             \
        *(f32x4*)&part[wv * 1536 + (nt * 16 + lj) * 16 + lg * 4] = acc[nt];  \
    __syncthreads();                                                         \
    _Pragma("unroll")                                                        \
    for (int j = 0; j < 3; ++j) {                                            \
        const int o2 = tid + j * 256;          /* pair idx: c*8 + p */       \
        const int c = o2 >> 3, p = o2 & 7;                                   \
        if (c < ncols) {                                                     \
            const int i0 = p * 2;                                            \
            const int oo = c * 16 + i0;                                      \
            float s0 = part[oo] + part[1536 + oo] + part[3072 + oo]          \
                     + part[4608 + oo] + conv_b[(LAY) * EMB + r0 + i0];      \
            float s1 = part[oo + 1] + part[1537 + oo] + part[3073 + oo]      \
                     + part[4609 + oo] + conv_b[(LAY) * EMB + r0 + i0 + 1];  \
            s0 = fmaxf(s0, 0.f); s1 = fmaxf(s1, 0.f);                        \
            const unsigned short h0 = f2bf(s0), h1 = f2bf(s1);               \
            const unsigned short l0 = f2bf(s0 - bf2f(h0));                   \
            const unsigned short l1 = f2bf(s1 - bf2f(h1));                   \
            unsigned short* dp = dst + c * XPITCH + bI * 32 + i0;            \
            st32g(dp,      (unsigned)h0 | ((unsigned)h1 << 16));             \
            st32g(dp + 16, (unsigned)l0 | ((unsigned)l1 << 16));             \
            if ((LAY) == NLAYER - 1 && c == 0) {                             \
                dout[3074 + r0 + i0]     = s0;                               \
                dout[3074 + r0 + i0 + 1] = s1;                               \
            }                                                                \
        }                                                                    \
    }                                                                        \
    if ((LAY) + 1 < NLAYER) {                                                \
        const unsigned tgt = (unsigned)((LAY) + 1);                          \
        asm volatile("s_waitcnt vmcnt(0)" ::: "memory");                     \
        __syncthreads();                                                     \
        if (tid == 0) stflag(&cflags[bI], tgt);                              \
        ISSUE_W((LAY) + 1, Wn);    /* stream next layer during barrier */    \
        asm volatile("" ::: "memory");                                       \
        if (bI == 0) {                                                       \
            for (int i = tid; i < CONV_WG; i += 256)                         \
                while (ldflag(&cflags[i]) < tgt)                             \
                    __builtin_amdgcn_s_sleep(1);                             \
            __syncthreads();                                                 \
            if (tid == 0) stflag(cepoch, tgt);                               \
        }                                                                    \
        if (tid == 0)                                                        \
            while (ldflag(cepoch) < tgt) __builtin_amdgcn_s_sleep(1);        \
        asm volatile("" ::: "memory");                                       \
        __syncthreads();                                                     \
    }                                                                        \
} while (0)

// ---------------- fused persistent kernel: 48 conv WGs + 192 LSTM WGs -----
__global__ __launch_bounds__(256, 1) void k_net(
    const int* __restrict__ xids, const float* __restrict__ emb1,
    const float* __restrict__ conv_w, const float* __restrict__ conv_b,
    unsigned short* __restrict__ x0buf, unsigned short* __restrict__ x1buf,
    const float* __restrict__ hstate, const float* __restrict__ cstate,
    const float* __restrict__ wih, const float* __restrict__ whh,
    const float* __restrict__ bih, const float* __restrict__ bhh,
    float* __restrict__ h1buf, float* __restrict__ h2buf,
    unsigned* __restrict__ cflags, unsigned* __restrict__ cepoch,
    unsigned* __restrict__ lflags, unsigned* __restrict__ lepoch,
    float* __restrict__ dout) {

    __shared__ __align__(16) unsigned short xs_hi[97 * CKP];   // 51216 B
    __shared__ __align__(16) unsigned short xs_lo[97 * CKP];   // 51216 B
    __shared__ __align__(16) float part[4 * 16 * 96];          // 24576 B
    __shared__ __align__(16) float hx[EMB], hb2[EMB], ex[EMB];
    __shared__ float g1s[16], g2s[16], c1s[4], c2s[4];

    const int tid = threadIdx.x;

    if (blockIdx.x < CONV_WG) {
        // ================= conv path: 16-row slab, split-bf16 MFMA ========
        const int wv = tid >> 6;           // wave 0..3 (K-split)
        const int ln = tid & 63;
        const int lj = ln & 15;            // A-row / B-col lane index
        const int lg = ln >> 4;            // k-group 0..3
        const int bI = blockIdx.x;
        const int r0 = bI * 16;

        float4 Wa[3][2][4], Wb[3][2][4];   // double-buffered weight slab
        ISSUE_W(0, Wa);

#pragma unroll 1
        for (int lay = 0; lay + 1 < NLAYER; lay += 2) {
            CONV_LAYER(lay, Wa, Wb);
            CONV_LAYER(lay + 1, Wb, Wa);
        }
        CONV_LAYER(NLAYER - 1, Wa, Wb);    // lay=94 (even), no prefetch
    } else {
        // ====== LSTM path: 97 ticks, skewed layers, fused W_ih1 ===========
        const int wg   = blockIdx.x - CONV_WG;    // 0..191
        const int l16  = tid & 15;
        const int r16  = tid >> 4;
        const int gate = r16 >> 2;
        const int jl   = r16 & 3;
        const int j0   = wg * 4;
        const int grow = gate * EMB + j0 + jl;

        float wi1r[48], wh1r[48], wi2r[48], wh2r[48];
        const float* wih1 = wih;
        const float* whh1 = whh;
        const float* wih2 = wih + (size_t)G4 * EMB;
        const float* whh2 = whh + (size_t)G4 * EMB;
#pragma unroll
        for (int i = 0; i < 48; ++i) {
            const int k = l16 + (i << 4);
            wi1r[i] = wih1[(size_t)grow * EMB + k];
            wh1r[i] = whh1[(size_t)grow * EMB + k];
            wi2r[i] = wih2[(size_t)grow * EMB + k];
            wh2r[i] = whh2[(size_t)grow * EMB + k];
        }
        const float b1 = bih[grow] + bhh[grow];
        const float b2 = bih[G4 + grow] + bhh[G4 + grow];

        if (tid < 4)      c1s[tid]     = cstate[j0 + tid];
        else if (tid < 8) c2s[tid - 4] = cstate[EMB + j0 + (tid - 4)];
        __syncthreads();

        for (int T = 0; T <= SEQ; ++T) {
            if (tid < 192) {
                if (T < SEQ) {     // stage emb1[x_T] (plain cached loads)
                    const int tok = xids[T];
                    float4 v = *(const float4*)(emb1 + (size_t)tok * EMB + tid * 4);
                    *(float4*)(ex + tid * 4) = v;
                }
                ull a, b;
                if (T == 0) {
                    a = ld64g(hstate + tid * 4);
                    b = ld64g(hstate + tid * 4 + 2);
                } else {
                    a = ld64g(h1buf + (T - 1) * EMB + tid * 4);
                    b = ld64g(h1buf + (T - 1) * EMB + tid * 4 + 2);
                }
                *(ull*)(hx + tid * 4)     = a;
                *(ull*)(hx + tid * 4 + 2) = b;
                ull a2 = 0, b2v = 0;
                if (T >= 1) {
                    if (T == 1) {
                        a2  = ld64g(hstate + EMB + tid * 4);
                        b2v = ld64g(hstate + EMB + tid * 4 + 2);
                    } else {
                        a2  = ld64g(h2buf + (T - 2) * EMB + tid * 4);
                        b2v = ld64g(h2buf + (T - 2) * EMB + tid * 4 + 2);
                    }
                }
                *(ull*)(hb2 + tid * 4)     = a2;
                *(ull*)(hb2 + tid * 4 + 2) = b2v;
            }
            __syncthreads();

            if (T < SEQ) {           // layer 1, step T (W_ih fused)
                float a = b1;
#pragma unroll
                for (int i = 0; i < 48; ++i)
                    a = fmaf(wi1r[i], ex[l16 + (i << 4)], a);
#pragma unroll
                for (int i = 0; i < 48; ++i)
                    a = fmaf(wh1r[i], hx[l16 + (i << 4)], a);
                a = red16(a);
                if (l16 == 0) g1s[r16] = a;
            }
            if (T >= 1) {            // layer 2, step T-1
                float b = b2;
#pragma unroll
                for (int i = 0; i < 48; ++i)
                    b = fmaf(wi2r[i], hx[l16 + (i << 4)], b);
#pragma unroll
                for (int i = 0; i < 48; ++i)
                    b = fmaf(wh2r[i], hb2[l16 + (i << 4)], b);
                b = red16(b);
                if (l16 == 0) g2s[r16] = b;
            }
            __syncthreads();

            if (tid < 4 && T < SEQ) {
                const int j = tid;
                const float i_ = sigmoidf_(g1s[j]);
                const float f_ = sigmoidf_(g1s[4 + j]);
                const float g_ = tanhf(g1s[8 + j]);
                const float o_ = sigmoidf_(g1s[12 + j]);
                const float c  = f_ * c1s[j] + i_ * g_;
                c1s[j] = c;
                const float h = o_ * tanhf(c);
                stf32g(&h1buf[T * EMB + j0 + j], h);
                if (T == SEQ - 1) {
                    dout[1 + j0 + j]    = h;   // h[0]
                    dout[1537 + j0 + j] = c;   // c[0]
                }
            } else if (tid >= 4 && tid < 8 && T >= 1) {
                const int j = tid - 4;
                const int s = T - 1;
                const float i_ = sigmoidf_(g2s[j]);
                const float f_ = sigmoidf_(g2s[4 + j]);
                const float g_ = tanhf(g2s[8 + j]);
                const float o_ = sigmoidf_(g2s[12 + j]);
                const float c  = f_ * c2s[j] + i_ * g_;
                c2s[j] = c;
                const float h = o_ * tanhf(c);
                stf32g(&h2buf[s * EMB + j0 + j], h);
                if (s == SEQ - 1) {
                    dout[1 + EMB + j0 + j]    = h;   // h[1]
                    dout[1537 + EMB + j0 + j] = c;   // c[1]
                }
            }
            if (T < SEQ)
                relbar(lflags, lepoch, LSTM_WG, wg, (unsigned)(T + 1));
        }
    }
}

// ---------------- deterministic scalar epilogue ---------------------------
__global__ void k_final(const float* __restrict__ pred_w,
                        const float* __restrict__ pred_b,
                        const float* __restrict__ m2w,
                        const float* __restrict__ m2b,
                        const float* __restrict__ prev,
                        float* __restrict__ dout) {
    __shared__ float red[256];
    const int tid = threadIdx.x;
    float p1 = 0.f;
    for (int idx = tid; idx < 2 * EMB; idx += 256) {
        const int l = idx / EMB;
        const int j = idx - l * EMB;
        p1 += dout[1537 + idx] * pred_w[j * 2 + l];   // feat = c.T interleave
    }
    float p2 = 0.f;
    for (int e = tid; e < EMB; e += 256)
        p2 += dout[3074 + e] * m2w[2 * e] + prev[e] * m2w[2 * e + 1];

    red[tid] = p1;
    __syncthreads();
    for (int s = 128; s > 0; s >>= 1) {
        if (tid < s) red[tid] += red[tid + s];
        __syncthreads();
    }
    if (tid == 0) dout[0] = red[0] + pred_b[0];
    __syncthreads();
    red[tid] = p2;
    __syncthreads();
    for (int s = 128; s > 0; s >>= 1) {
        if (tid < s) red[tid] += red[tid + s];
        __syncthreads();
    }
    if (tid == 0) dout[3073] = red[0] + m2b[0];
}

extern "C" void kernel_launch(void* const* d_in, const int* in_sizes, int n_in,
                              void* d_out, int out_size, void* d_ws, size_t ws_size,
                              hipStream_t stream) {
    const int*   x      = (const int*)d_in[0];
    const float* hstate = (const float*)d_in[1];
    const float* cstate = (const float*)d_in[2];
    const float* prev   = (const float*)d_in[3];
    const float* emb1   = (const float*)d_in[4];
    const float* emb2   = (const float*)d_in[5];
    const float* wih    = (const float*)d_in[6];
    const float* whh    = (const float*)d_in[7];
    const float* bih    = (const float*)d_in[8];
    const float* bhh    = (const float*)d_in[9];
    const float* predw  = (const float*)d_in[10];
    const float* predb  = (const float*)d_in[11];
    const float* convw  = (const float*)d_in[12];
    const float* convb  = (const float*)d_in[13];
    const float* m2w    = (const float*)d_in[14];
    const float* m2b    = (const float*)d_in[15];
    float* out = (float*)d_out;

    unsigned* wsw = (unsigned*)d_ws;
    unsigned* cflags = wsw;            // [0..48)
    unsigned* cepoch = wsw + 64;
    unsigned* lflags = wsw + 128;      // [128..320)
    unsigned* lepoch = wsw + 384;
    float* base  = (float*)d_ws + 1024;
    float* h1buf = base;                               // 96*768 f32
    float* h2buf = h1buf + SEQ * EMB;                  // 96*768 f32
    unsigned short* x0buf = (unsigned short*)(h2buf + SEQ * EMB); // 96*1536 u16
    unsigned short* x1buf = x0buf + SEQ * XPITCH;                 // 96*1536 u16

    hipMemsetAsync(d_ws, 0, 4096, stream);                   // flags + epochs
    hipMemsetAsync(d_out, 0, out_size * sizeof(float), stream);

    k_embed<<<96, 256, 0, stream>>>(x, emb2, x0buf);
    k_net<<<CONV_WG + LSTM_WG, 256, 0, stream>>>(
        x, emb1, convw, convb, x0buf, x1buf,
        hstate, cstate, wih, whh, bih, bhh, h1buf, h2buf,
        cflags, cepoch, lflags, lepoch, out);
    k_final<<<1, 256, 0, stream>>>(predw, predb, m2w, m2b, prev, out);
}